// Round 8
// baseline (1676.522 us; speedup 1.0000x reference)
//
#include <hip/hip_runtime.h>
#include <math.h>

#define NQ 16
#define NL 5
#define NB 64
#define NC 10
#define NBLK 1024
#define THR 256

// ---- workspace layout (bytes) ----
#define OFF_GATES 33554432u                    // state: [0, 32MB)
#define OFF_CRX   (OFF_GATES + 163840u)
#define OFF_ZPART (OFF_CRX + 1024u)
#define OFF_CNT   (OFF_ZPART + 32768u)
#define CNT_WORDS (12 * 64 * 32)               // 12 phases x 64 subcounters x 128B stride
#define CNT_BYTES (CNT_WORDS * 4u)

__device__ __forceinline__ float2 cmul(float2 a, float2 b) {
  return make_float2(a.x*b.x - a.y*b.y, a.x*b.y + a.y*b.x);
}
__device__ __forceinline__ float2 cadd(float2 a, float2 b) {
  return make_float2(a.x + b.x, a.y + b.y);
}
// LDS swizzle (12-bit domain): phys = i ^ ((i>>4)&0xF) ^ (((i>>8)&1)<<4).
__device__ __forceinline__ int sw2(int i) { return i ^ ((i >> 4) & 0xF) ^ (((i >> 8) & 1) << 4); }

// ---------------- hand-rolled grid barrier (exactly-resident grid) ----------------
// Per-phase fresh counters (zeroed each launch): no sense reversal needed.
// 64 subcounters, 128B apart -> <=16 same-address atomics each.
// __threadfence() = agent-scope fence: on gfx950 the backend emits the L2
// writeback (release) / invalidate (acquire) needed across XCDs.
__device__ __forceinline__ void grid_barrier(unsigned* cnt, int phase) {
  __syncthreads();                      // all block threads done (drains their stores)
  unsigned* base = cnt + phase * (64 * 32);
  if (threadIdx.x == 0) {
    __threadfence();                    // release (XCD L2 writeback)
    __hip_atomic_fetch_add(base + (blockIdx.x & 63) * 32, 1u,
                           __ATOMIC_RELEASE, __HIP_MEMORY_SCOPE_AGENT);
    unsigned sum;
    do {
      sum = 0;
      #pragma unroll
      for (int i = 0; i < 64; ++i)
        sum += __hip_atomic_load(base + i * 32, __ATOMIC_RELAXED, __HIP_MEMORY_SCOPE_AGENT);
      if (sum < NBLK) __builtin_amdgcn_s_sleep(2);
    } while (sum < NBLK);
    __threadfence();                    // acquire (invalidate stale caches)
  }
  __syncthreads();
}

// ---------------- register-group gate primitives ----------------
template<int K, int GB>
__device__ __forceinline__ void g1q(float2* v, const float2* U) {
  #pragma unroll
  for (int m = 0; m < (1 << K); ++m) {
    if (!(m & (1 << GB))) {
      const int m2 = m | (1 << GB);
      float2 a = v[m], b = v[m2];
      v[m]  = cadd(cmul(U[0], a), cmul(U[1], b));
      v[m2] = cadd(cmul(U[2], a), cmul(U[3], b));
    }
  }
}
template<int K, int CP, int TP>
__device__ __forceinline__ void gcrx(float2* v, float c, float s) {
  #pragma unroll
  for (int m = 0; m < (1 << K); ++m) {
    if ((m & (1 << CP)) && !(m & (1 << TP))) {
      const int m2 = m | (1 << TP);
      float2 a = v[m], b = v[m2];
      v[m]  = make_float2(c * a.x + s * b.y, c * a.y - s * b.x);
      v[m2] = make_float2(c * b.x + s * a.y, c * b.y - s * a.x);
    }
  }
}
// plain RX on group-bit TP (ctrl-outside-group CRX; identity when c=1,s=0)
template<int K, int TP>
__device__ __forceinline__ void grx1(float2* v, float c, float s) {
  #pragma unroll
  for (int m = 0; m < (1 << K); ++m) {
    if (!(m & (1 << TP))) {
      const int m2 = m | (1 << TP);
      float2 a = v[m], b = v[m2];
      v[m]  = make_float2(c * a.x + s * b.y, c * a.y - s * b.x);
      v[m2] = make_float2(c * b.x + s * a.y, c * b.y - s * a.x);
    }
  }
}

__device__ __forceinline__ void loadU(const float2* __restrict__ G, int w, float2* U) {
  const float4* p = (const float4*)(G + w * 4);
  float4 a = p[0], b = p[1];
  U[0] = make_float2(a.x, a.y); U[1] = make_float2(a.z, a.w);
  U[2] = make_float2(b.x, b.y); U[3] = make_float2(b.z, b.w);
}

// ---------------- role: precompute fused U = Rot * RX ; CRX cos/sin ----------------
__device__ void precompute_work(int idx, const float* __restrict__ x,
                                const float* __restrict__ rot, const float* __restrict__ crx,
                                float2* __restrict__ gates1q, float2* __restrict__ crxcs) {
  if (idx < NB * NL * NQ) {
    int w = idx % NQ; int n = (idx / NQ) % NL; int b = idx / (NQ * NL);
    float xv = x[b * NQ + w];
    float sx, cx; sincosf(0.5f * xv, &sx, &cx);
    float phi = rot[(n * NQ + w) * 3 + 0];
    float th  = rot[(n * NQ + w) * 3 + 1];
    float om  = rot[(n * NQ + w) * 3 + 2];
    float st, ct; sincosf(0.5f * th, &st, &ct);
    float sa, ca; sincosf(0.5f * (phi + om), &sa, &ca);
    float sd, cd; sincosf(0.5f * (phi - om), &sd, &cd);
    float2 r00 = make_float2( ca * ct, -sa * ct);
    float2 r01 = make_float2(-cd * st, -sd * st);
    float2 r10 = make_float2( cd * st, -sd * st);
    float2 r11 = make_float2( ca * ct,  sa * ct);
    float2 rc = make_float2(cx, 0.f), rs = make_float2(0.f, -sx);
    float2* dst = gates1q + (size_t)idx * 4;
    dst[0] = cadd(cmul(r00, rc), cmul(r01, rs));
    dst[1] = cadd(cmul(r00, rs), cmul(r01, rc));
    dst[2] = cadd(cmul(r10, rc), cmul(r11, rs));
    dst[3] = cadd(cmul(r10, rs), cmul(r11, rc));
  }
  int c = idx - NB * NL * NQ;
  if (c >= 0 && c < NL * NQ) {
    float s, cc; sincosf(0.5f * crx[c], &s, &cc);
    crxcs[c] = make_float2(cc, s);
  }
}

// ---------------- role A: wires 0..11 (1q 0..11, crx (0,1)..(10,11)) ----------------
// Tile = 4096 contiguous amps (bits 12..15 = t), 32 KB LDS, 2 block barriers.
__device__ void a_work(int k, bool first, int bid,
                       const float2* __restrict__ gates1q, const float2* __restrict__ crxcs,
                       float2* __restrict__ state, float2* __restrict__ amp) {
  const int tid = threadIdx.x;
  const int t = bid >> 6, b = bid & 63;
  if (first && t != 0) return;   // layer-0: only tile 0 is populated from |0..0>
  const float2* G  = gates1q + (size_t)(b * NL + k) * NQ * 4;
  const float2* CS = crxcs + k * NQ;
  const size_t gbase = ((size_t)b << 16) | ((size_t)t << 12);

  float2 UA[4], UB[4], UC[4], UD[4];
  float2 v[16];

  // ---- P1: global -> regs (group = bits {0,1,2,3}) -> gates -> LDS ----
  if (first) {
    #pragma unroll
    for (int m = 0; m < 16; ++m) v[m] = make_float2(0.f, 0.f);
    if (tid == 0) v[0] = make_float2(1.f, 0.f);
  } else {
    const float4* st4 = (const float4*)(state + gbase + ((size_t)tid << 4));
    #pragma unroll
    for (int kk = 0; kk < 8; ++kk) {
      float4 d = st4[kk];
      v[2*kk]   = make_float2(d.x, d.y);
      v[2*kk+1] = make_float2(d.z, d.w);
    }
  }
  loadU(G,0,UA); loadU(G,1,UB); loadU(G,2,UC); loadU(G,3,UD);
  {
    float2 k0 = CS[0], k1 = CS[1], k2 = CS[2];
    g1q<4,0>(v,UA); g1q<4,1>(v,UB); g1q<4,2>(v,UC); g1q<4,3>(v,UD);
    gcrx<4,0,1>(v,k0.x,k0.y); gcrx<4,1,2>(v,k1.x,k1.y); gcrx<4,2,3>(v,k2.x,k2.y);
  }
  {
    const int sb = sw2(tid << 4);
    #pragma unroll
    for (int m = 0; m < 16; ++m) amp[sb ^ m] = v[m];   // sw2(l0|m) = sw2(l0)^m
  }
  __syncthreads();

  // ---- P2: LDS sweep, group = bits {4,5,6,7} ----
  loadU(G,4,UA); loadU(G,5,UB); loadU(G,6,UC); loadU(G,7,UD);
  {
    float2 k3 = CS[3], k0 = CS[4], k1 = CS[5], k2 = CS[6];
    const int base = (tid & 15) | ((tid >> 4) << 8);   // bits 0..3, 8..11
    const int sb = sw2(base);
    #pragma unroll
    for (int m = 0; m < 16; ++m) v[m] = amp[sb ^ (m * 17)];  // sw2(m<<4) = m<<4 | m
    g1q<4,0>(v,UA); g1q<4,1>(v,UB); g1q<4,2>(v,UC); g1q<4,3>(v,UD);
    const bool pd = (base >> 3) & 1;   // crx(3,4): ctrl = bit 3 (in base)
    grx1<4,0>(v, pd ? k3.x : 1.f, pd ? k3.y : 0.f);
    gcrx<4,0,1>(v,k0.x,k0.y); gcrx<4,1,2>(v,k1.x,k1.y); gcrx<4,2,3>(v,k2.x,k2.y);
    #pragma unroll
    for (int m = 0; m < 16; ++m) amp[sb ^ (m * 17)] = v[m];
  }
  __syncthreads();

  // ---- P3: LDS read, group = bits {8,9,10,11} -> gates -> global (coalesced) ----
  loadU(G,8,UA); loadU(G,9,UB); loadU(G,10,UC); loadU(G,11,UD);
  {
    float2 k3 = CS[7], k0 = CS[8], k1 = CS[9], k2 = CS[10];
    const int base = tid;              // bits 0..7
    const int sb = sw2(base);
    #pragma unroll
    for (int m = 0; m < 16; ++m)
      v[m] = amp[sb ^ ((m << 8) | ((m & 1) << 4))];    // sw2(m<<8)
    g1q<4,0>(v,UA); g1q<4,1>(v,UB); g1q<4,2>(v,UC); g1q<4,3>(v,UD);
    const bool pd = (base >> 7) & 1;   // crx(7,8): ctrl = bit 7 (in base)
    grx1<4,0>(v, pd ? k3.x : 1.f, pd ? k3.y : 0.f);
    gcrx<4,0,1>(v,k0.x,k0.y); gcrx<4,1,2>(v,k1.x,k1.y); gcrx<4,2,3>(v,k2.x,k2.y);
    float2* stw = state + gbase;
    #pragma unroll
    for (int m = 0; m < 16; ++m) stw[base | (m << 8)] = v[m];  // 8B/lane, coalesced per m
  }
}

// ---------------- role B: wires 12..15 + wrap (1q 12..15, crx (11,12)..(15,0)) ----------------
// Register-only: group = bits {0,12..15} (32 amps/thread). Blocks 0..511:
// j = bid>>6 in [0,8), b = bid&63; tb = j>>1, tid512 = ((j&1)<<8)|tid.
__device__ void b_work(int k, bool lfirst, bool last, int bid,
                       const float2* __restrict__ gates1q, const float2* __restrict__ crxcs,
                       float2* __restrict__ state, float* __restrict__ zpart,
                       float* __restrict__ red_mem) {
  const int tid = threadIdx.x;
  const int j = bid >> 6, b = bid & 63;
  const int tb = j >> 1;
  const int tid512 = ((j & 1) << 8) | tid;
  const float2* G  = gates1q + (size_t)(b * NL + k) * NQ * 4;
  const float2* CS = crxcs + k * NQ;
  const int base = (tb << 10) | (tid512 << 1);   // amp bits 1..11 (bit0 in group)
  float4* st4 = (float4*)(state + (((size_t)b) << 16));

  float2 v[32];   // m = hi*2 + p0: pos0 = bit0 (wire0), pos1..4 = bits 12..15
  #pragma unroll
  for (int hi = 0; hi < 16; ++hi) {
    if (lfirst && hi >= 1) {   // after layer-0 A, amps with bits 12..15 != 0 are zero
      v[2*hi] = make_float2(0.f, 0.f); v[2*hi+1] = make_float2(0.f, 0.f);
      continue;
    }
    float4 d = st4[((hi << 12) | base) >> 1];
    v[2*hi]   = make_float2(d.x, d.y);
    v[2*hi+1] = make_float2(d.z, d.w);
  }

  float2 U[4];
  loadU(G,12,U); g1q<5,1>(v,U);
  loadU(G,13,U); g1q<5,2>(v,U);
  loadU(G,14,U); g1q<5,3>(v,U);
  loadU(G,15,U); g1q<5,4>(v,U);
  {
    float2 kB = CS[11];                 // crx(11,12): ctrl = bit 11 = tb bit1 (uniform)
    if (tb & 2) grx1<5,1>(v, kB.x, kB.y);
    float2 k0 = CS[12], k1 = CS[13], k2 = CS[14], kF = CS[15];
    gcrx<5,1,2>(v,k0.x,k0.y);           // crx(12,13)
    gcrx<5,2,3>(v,k1.x,k1.y);           // crx(13,14)
    gcrx<5,3,4>(v,k2.x,k2.y);           // crx(14,15)
    gcrx<5,4,0>(v,kF.x,kF.y);           // crx(15,0)
  }

  if (!last) {
    #pragma unroll
    for (int hi = 0; hi < 16; ++hi)
      st4[((hi << 12) | base) >> 1] =
        make_float4(v[2*hi].x, v[2*hi].y, v[2*hi+1].x, v[2*hi+1].y);
  } else {
    // Z-expectation partials; state never stored.
    float S[16], prtot = 0.f, s0 = 0.f;
    #pragma unroll
    for (int hi = 0; hi < 16; ++hi) {
      float p0 = v[2*hi].x*v[2*hi].x + v[2*hi].y*v[2*hi].y;
      float p1 = v[2*hi+1].x*v[2*hi+1].x + v[2*hi+1].y*v[2*hi+1].y;
      S[hi] = p0 + p1; prtot += S[hi]; s0 += p0 - p1;
    }
    float zacc[16];
    zacc[0] = s0;
    #pragma unroll
    for (int w = 1; w < 12; ++w) {
      int bit = (w < 10) ? ((tid512 >> (w - 1)) & 1) : ((tb >> (w - 10)) & 1);
      zacc[w] = bit ? -prtot : prtot;
    }
    #pragma unroll
    for (int w = 12; w < 16; ++w) {
      float s = 0.f;
      #pragma unroll
      for (int hi = 0; hi < 16; ++hi) s += ((hi >> (w - 12)) & 1) ? -S[hi] : S[hi];
      zacc[w] = s;
    }
    float (*red)[16] = (float(*)[16])red_mem;   // reuse block LDS
    const int lane = tid & 63, wv = tid >> 6;   // 4 waves
    #pragma unroll
    for (int w = 0; w < 16; ++w) {
      float vv = zacc[w];
      #pragma unroll
      for (int off = 32; off > 0; off >>= 1) vv += __shfl_xor(vv, off);
      if (lane == 0) red[wv][w] = vv;
    }
    __syncthreads();
    if (tid < 16) {
      float s = 0.f;
      #pragma unroll
      for (int kk = 0; kk < 4; ++kk) s += red[kk][tid];
      zpart[(b * 8 + j) * 16 + tid] = s;
    }
  }
}

// ---------------- role final: z reduce over 8 B-blocks, logits, log_softmax ----------------
__device__ void final_work(int bid, const float* __restrict__ zpart,
                           const float* __restrict__ fc_w, const float* __restrict__ fc_b,
                           float* __restrict__ out) {
  if (bid >= NB || threadIdx.x >= 64) return;
  const int b = bid, lane = threadIdx.x;
  float z = 0.f;
  if (lane < 16) {
    #pragma unroll
    for (int j = 0; j < 8; ++j) z += zpart[(b * 8 + j) * 16 + lane];
  }
  float acc = (lane < NC) ? fc_b[lane] : -1e30f;
  #pragma unroll
  for (int w = 0; w < 16; ++w) {
    float zw = __shfl(z, w);
    if (lane < NC) acc += fc_w[lane * 16 + w] * zw;
  }
  float m = -1e30f;
  #pragma unroll
  for (int jj = 0; jj < NC; ++jj) m = fmaxf(m, __shfl(acc, jj));
  float e = (lane < NC) ? expf(acc - m) : 0.f;
  float s = 0.f;
  #pragma unroll
  for (int jj = 0; jj < NC; ++jj) s += __shfl(e, jj);
  if (lane < NC) out[b * NC + lane] = acc - m - logf(s);
}

// ---------------- persistent kernel: ordinary launch, exactly-resident grid ----------------
// 1024 blocks x 256 thr, 32 KB LDS, __launch_bounds__(256,4) -> 4 blocks/CU (VGPR<=128,
// LDS allows 5) -> all 1024 blocks resident on 256 CUs; DIY grid barrier is safe.
__global__ __launch_bounds__(THR, 4) void mega_kernel(
    const float* __restrict__ x, const float* __restrict__ rot, const float* __restrict__ crx,
    const float* __restrict__ fc_w, const float* __restrict__ fc_b, float* __restrict__ out,
    float2* __restrict__ gates1q, float2* __restrict__ crxcs,
    float2* __restrict__ state, float* __restrict__ zpart, unsigned* __restrict__ cnt) {
  __shared__ __align__(16) float2 amp[4096];   // 32 KB
  const int bid = blockIdx.x;

  precompute_work(bid * THR + threadIdx.x, x, rot, crx, gates1q, crxcs);
  grid_barrier(cnt, 0);

  for (int k = 0; k < NL; ++k) {
    a_work(k, k == 0, bid, gates1q, crxcs, state, amp);
    grid_barrier(cnt, 1 + 2 * k);
    if (bid < 512) b_work(k, k == 0, k == NL - 1, bid, gates1q, crxcs, state, zpart, (float*)amp);
    grid_barrier(cnt, 2 + 2 * k);
  }

  final_work(bid, zpart, fc_w, fc_b, out);
}

extern "C" void kernel_launch(void* const* d_in, const int* in_sizes, int n_in,
                              void* d_out, int out_size, void* d_ws, size_t ws_size,
                              hipStream_t stream) {
  const float* x    = (const float*)d_in[0];
  const float* rot  = (const float*)d_in[1];
  const float* crx  = (const float*)d_in[2];
  const float* fc_w = (const float*)d_in[3];
  const float* fc_b = (const float*)d_in[4];
  float* out = (float*)d_out;

  char* ws = (char*)d_ws;
  float2* state   = (float2*)ws;
  float2* gates1q = (float2*)(ws + OFF_GATES);
  float2* crxcs   = (float2*)(ws + OFF_CRX);
  float*  zpart   = (float*)(ws + OFF_ZPART);
  unsigned* cnt   = (unsigned*)(ws + OFF_CNT);

  // zero the barrier counters (ws is re-poisoned 0xAA before every timed call)
  hipMemsetAsync(cnt, 0, CNT_BYTES, stream);

  mega_kernel<<<NBLK, THR, 0, stream>>>(x, rot, crx, fc_w, fc_b, out,
                                        gates1q, crxcs, state, zpart, cnt);
}